// Round 1
// baseline (6325.211 us; speedup 1.0000x reference)
//
#include <hip/hip_runtime.h>
#include <math.h>

#define HH 4
#define DD 512
#define FF 1024          // 2*DD floats per complex vector
#define NN 2048
#define KK 4
#define TMAXI 4
#define THRESHV 0.99f
#define EPSV 1e-6f

// ---------------- init: broadcast psi -> psi_h ----------------
__global__ void k_init_psih(const float* __restrict__ psi, float* __restrict__ psi_h, int total) {
    int i = blockIdx.x * 256 + threadIdx.x;
    if (i >= total) return;
    int f = i & (FF - 1);
    int b = i >> 12;               // i / (HH*FF)
    psi_h[i] = psi[(size_t)b * FF + f];
}

// ---------------- u_halt norms ----------------
__global__ void k_unorm(const float* __restrict__ u_halt, float* __restrict__ norm_inv) {
    __shared__ float red[256];
    int tid = threadIdx.x;
    for (int h = 0; h < HH; ++h) {
        float s = 0.f;
        for (int i = tid; i < FF; i += 256) { float v = u_halt[h * FF + i]; s += v * v; }
        red[tid] = s; __syncthreads();
        for (int off = 128; off > 0; off >>= 1) {
            if (tid < off) red[tid] += red[tid + off];
            __syncthreads();
        }
        if (tid == 0) norm_inv[h] = 1.0f / sqrtf(red[0] + EPSV);
        __syncthreads();
    }
}

// ---------------- pool over heads -> feat ----------------
__global__ void k_pool(const float* __restrict__ psi_h, float* __restrict__ feat, int total) {
    int i = blockIdx.x * 256 + threadIdx.x;
    if (i >= total) return;
    int f = i & (FF - 1); int b = i >> 10;
    const float* p = psi_h + (size_t)b * HH * FF + f;
    feat[i] = 0.25f * (p[0] + p[FF] + p[2 * FF] + p[3 * FF]);
}

// ---------------- scores GEMM: C[r][n'] = sum_k A[r][k]*B[n'][k] ----------------
// A: RC x 1024 (row-major), B: 8192 x 1024 (row-major), C: RC x 8192
#define BKK 32
__global__ __launch_bounds__(256) void k_gemm(const float* __restrict__ A,
                                              const float* __restrict__ Bm,
                                              float* __restrict__ C) {
    __shared__ float As[64][BKK + 4];   // pitch 36
    __shared__ float Bs[64][BKK + 4];
    int tid = threadIdx.x;
    int tx = tid & 15;       // col group
    int ty = tid >> 4;       // row group
    int row0 = blockIdx.y * 64;
    int col0 = blockIdx.x * 64;
    float acc[4][4] = {};
    int lrow = tid >> 2;           // 0..63
    int lk = (tid & 3) * 8;        // 0,8,16,24
    const float* Ag = A + (size_t)(row0 + lrow) * FF + lk;
    const float* Bg = Bm + (size_t)(col0 + lrow) * FF + lk;
    for (int kb = 0; kb < FF; kb += BKK) {
        float4 a0 = *(const float4*)(Ag + kb);
        float4 a1 = *(const float4*)(Ag + kb + 4);
        float4 b0 = *(const float4*)(Bg + kb);
        float4 b1 = *(const float4*)(Bg + kb + 4);
        *(float4*)&As[lrow][lk]     = a0;
        *(float4*)&As[lrow][lk + 4] = a1;
        *(float4*)&Bs[lrow][lk]     = b0;
        *(float4*)&Bs[lrow][lk + 4] = b1;
        __syncthreads();
        #pragma unroll
        for (int k = 0; k < BKK; k += 4) {
            float4 av[4], bv[4];
            #pragma unroll
            for (int i = 0; i < 4; i++) av[i] = *(const float4*)&As[ty + 16 * i][k];
            #pragma unroll
            for (int j = 0; j < 4; j++) bv[j] = *(const float4*)&Bs[tx + 16 * j][k];
            #pragma unroll
            for (int i = 0; i < 4; i++)
                #pragma unroll
                for (int j = 0; j < 4; j++)
                    acc[i][j] += av[i].x * bv[j].x + av[i].y * bv[j].y +
                                 av[i].z * bv[j].z + av[i].w * bv[j].w;
        }
        __syncthreads();
    }
    #pragma unroll
    for (int i = 0; i < 4; i++) {
        float* Cr = C + (size_t)(row0 + ty + 16 * i) * (HH * NN) + col0;
        #pragma unroll
        for (int j = 0; j < 4; j++) Cr[tx + 16 * j] = acc[i][j];
    }
}

// ---------------- softmax + top-4 per (row, head) ----------------
__global__ __launch_bounds__(256) void k_softtop(const float* __restrict__ Sc,
                                                 float* __restrict__ topw, int* __restrict__ topi,
                                                 int row0) {
    int r = blockIdx.x, h = blockIdx.y;
    int tid = threadIdx.x;
    const float* S = Sc + (size_t)r * (HH * NN) + h * NN;
    float v[8];
    #pragma unroll
    for (int j = 0; j < 8; j++) v[j] = S[tid + 256 * j];
    __shared__ float rv[256];
    __shared__ int ri[256];
    // row max
    float bm = v[0];
    #pragma unroll
    for (int j = 1; j < 8; j++) bm = fmaxf(bm, v[j]);
    rv[tid] = bm; __syncthreads();
    for (int off = 128; off > 0; off >>= 1) {
        if (tid < off) rv[tid] = fmaxf(rv[tid], rv[tid + off]);
        __syncthreads();
    }
    float smax = rv[0]; __syncthreads();
    // sum exp
    float se = 0.f;
    #pragma unroll
    for (int j = 0; j < 8; j++) se += expf(v[j] - smax);
    rv[tid] = se; __syncthreads();
    for (int off = 128; off > 0; off >>= 1) {
        if (tid < off) rv[tid] += rv[tid + off];
        __syncthreads();
    }
    float Zinv = 1.0f / rv[0]; __syncthreads();
    int gbh = (row0 + r) * HH + h;
    for (int k = 0; k < KK; k++) {
        float bv = -INFINITY; int bi = NN;
        #pragma unroll
        for (int j = 0; j < 8; j++) {
            int n = tid + 256 * j;
            if (v[j] > bv) { bv = v[j]; bi = n; }
        }
        rv[tid] = bv; ri[tid] = bi; __syncthreads();
        for (int off = 128; off > 0; off >>= 1) {
            if (tid < off) {
                float ov = rv[tid + off]; int oi = ri[tid + off];
                if (ov > rv[tid] || (ov == rv[tid] && oi < ri[tid])) { rv[tid] = ov; ri[tid] = oi; }
            }
            __syncthreads();
        }
        float wv = rv[0]; int wi = ri[0]; __syncthreads();
        if (tid == (wi & 255)) v[wi >> 8] = -INFINITY;
        if (tid == 0) { topw[gbh * KK + k] = expf(wv - smax) * Zinv; topi[gbh * KK + k] = wi; }
    }
}

// ---------------- wave reduce ----------------
__device__ inline float wred(float v) {
    #pragma unroll
    for (int m = 1; m < 64; m <<= 1) v += __shfl_xor(v, m, 64);
    return v;
}

// ---------------- projection + normalize (psi_h updated in place) ----------------
__global__ __launch_bounds__(256) void k_solve(float* __restrict__ psi_h,
                                               const float* __restrict__ bank_vals,
                                               const float* __restrict__ topw,
                                               const int* __restrict__ topi) {
    int bh = blockIdx.x;
    int h = bh & (HH - 1);
    int tid = threadIdx.x;
    int wid = tid >> 6, lane = tid & 63;
    float w[KK]; int ix[KK];
    #pragma unroll
    for (int k = 0; k < KK; k++) { w[k] = topw[bh * KK + k]; ix[k] = topi[bh * KK + k]; }
    float* P = psi_h + (size_t)bh * FF;
    float pr[2], pim[2], Ur[KK][2], Ui[KK][2];
    #pragma unroll
    for (int s = 0; s < 2; s++) {
        int d = tid + 256 * s;
        pr[s] = P[2 * d]; pim[s] = P[2 * d + 1];
        #pragma unroll
        for (int k = 0; k < KK; k++) {
            const float* Vp = bank_vals + ((size_t)h * NN + ix[k]) * FF;
            Ur[k][s] = Vp[2 * d] * w[k];
            Ui[k][s] = Vp[2 * d + 1] * w[k];
        }
    }
    // partials: m (4 complex), G upper triangle (10 complex) -> 28 floats
    float part[28];
    #pragma unroll
    for (int t = 0; t < 28; t++) part[t] = 0.f;
    #pragma unroll
    for (int s = 0; s < 2; s++) {
        #pragma unroll
        for (int k = 0; k < KK; k++) {
            part[2 * k]     += Ur[k][s] * pr[s] + Ui[k][s] * pim[s];   // conj(U)·psi
            part[2 * k + 1] += Ur[k][s] * pim[s] - Ui[k][s] * pr[s];
        }
        int t = 8;
        #pragma unroll
        for (int k = 0; k < KK; k++)
            #pragma unroll
            for (int j = k; j < KK; j++) {
                part[t]     += Ur[k][s] * Ur[j][s] + Ui[k][s] * Ui[j][s];  // conj(Uk)·Uj
                part[t + 1] += Ur[k][s] * Ui[j][s] - Ui[k][s] * Ur[j][s];
                t += 2;
            }
    }
    __shared__ float xw[4][28];
    #pragma unroll
    for (int t = 0; t < 28; t++) {
        float r = wred(part[t]);
        if (lane == 0) xw[wid][t] = r;
    }
    __syncthreads();
    float red[28];
    #pragma unroll
    for (int t = 0; t < 28; t++) red[t] = xw[0][t] + xw[1][t] + xw[2][t] + xw[3][t];

    float mr[KK], mi[KK], Gr[KK][KK], Gi[KK][KK];
    #pragma unroll
    for (int k = 0; k < KK; k++) { mr[k] = red[2 * k]; mi[k] = red[2 * k + 1]; }
    {
        int t = 8;
        #pragma unroll
        for (int k = 0; k < KK; k++)
            #pragma unroll
            for (int j = k; j < KK; j++) {
                Gr[k][j] = red[t]; Gi[k][j] = red[t + 1];
                if (j > k) { Gr[j][k] = red[t]; Gi[j][k] = -red[t + 1]; }
                t += 2;
            }
    }
    #pragma unroll
    for (int k = 0; k < KK; k++) { Gr[k][k] += EPSV; Gi[k][k] = 0.f; }

    // complex Cholesky G = L L^H
    float Lr[KK][KK], Li[KK][KK];
    #pragma unroll
    for (int j = 0; j < KK; j++) {
        float s = Gr[j][j];
        #pragma unroll
        for (int p = 0; p < KK; p++) if (p < j) s -= Lr[j][p] * Lr[j][p] + Li[j][p] * Li[j][p];
        float ljj = sqrtf(fmaxf(s, 1e-30f));
        Lr[j][j] = ljj; Li[j][j] = 0.f;
        float inv = 1.0f / ljj;
        #pragma unroll
        for (int k = 0; k < KK; k++) {
            if (k > j) {
                float ar = Gr[k][j], ai = Gi[k][j];
                #pragma unroll
                for (int p = 0; p < KK; p++) if (p < j) {
                    ar -= Lr[k][p] * Lr[j][p] + Li[k][p] * Li[j][p];   // l[k][p]*conj(l[j][p])
                    ai -= Li[k][p] * Lr[j][p] - Lr[k][p] * Li[j][p];
                }
                Lr[k][j] = ar * inv; Li[k][j] = ai * inv;
            }
        }
    }
    // forward L y = m
    float yr[KK], yi[KK];
    #pragma unroll
    for (int j = 0; j < KK; j++) {
        float ar = mr[j], ai = mi[j];
        #pragma unroll
        for (int p = 0; p < KK; p++) if (p < j) {
            ar -= Lr[j][p] * yr[p] - Li[j][p] * yi[p];
            ai -= Lr[j][p] * yi[p] + Li[j][p] * yr[p];
        }
        float inv = 1.0f / Lr[j][j];
        yr[j] = ar * inv; yi[j] = ai * inv;
    }
    // backward L^H x = y
    float xr[KK], xi2[KK];
    #pragma unroll
    for (int j = KK - 1; j >= 0; j--) {
        float ar = yr[j], ai = yi[j];
        #pragma unroll
        for (int p = 0; p < KK; p++) if (p > j) {
            ar -= Lr[p][j] * xr[p] + Li[p][j] * xi2[p];   // conj(l[p][j])*x[p]
            ai -= Lr[p][j] * xi2[p] - Li[p][j] * xr[p];
        }
        float inv = 1.0f / Lr[j][j];
        xr[j] = ar * inv; xi2[j] = ai * inv;
    }
    // proj + norm
    float pjr[2], pji[2];
    float sqp = 0.f;
    #pragma unroll
    for (int s = 0; s < 2; s++) {
        float ar = 0.f, ai = 0.f;
        #pragma unroll
        for (int k = 0; k < KK; k++) {
            ar += Ur[k][s] * xr[k] - Ui[k][s] * xi2[k];
            ai += Ur[k][s] * xi2[k] + Ui[k][s] * xr[k];
        }
        pjr[s] = ar; pji[s] = ai;
        sqp += ar * ar + ai * ai;
    }
    float rs = wred(sqp);
    __syncthreads();
    if (lane == 0) xw[wid][0] = rs;
    __syncthreads();
    float sq = xw[0][0] + xw[1][0] + xw[2][0] + xw[3][0];
    float rn = 1.0f / sqrtf(fmaxf(sq, 1e-6f));
    #pragma unroll
    for (int s = 0; s < 2; s++) {
        int d = tid + 256 * s;
        P[2 * d] = pjr[s] * rn;
        P[2 * d + 1] = pji[s] * rn;
    }
}

// ---------------- halting + merged accumulation ----------------
__global__ __launch_bounds__(256) void k_halt(const float* __restrict__ psi_h,
                                              const float* __restrict__ u_halt,
                                              const float* __restrict__ norm_inv,
                                              const float* __restrict__ W_halt,
                                              const float* __restrict__ b_halt,
                                              const float* __restrict__ head_mix,
                                              float* __restrict__ merged,
                                              float* __restrict__ cum,
                                              float* __restrict__ cost,
                                              int* __restrict__ halted,
                                              int is_last) {
    int b = blockIdx.x; int tid = threadIdx.x;
    int wid = tid >> 6, lane = tid & 63;
    const float* P = psi_h + (size_t)b * HH * FF;
    float part[9];
    #pragma unroll
    for (int t = 0; t < 9; t++) part[t] = 0.f;
    #pragma unroll
    for (int s = 0; s < 2; s++) {
        int f = 2 * (tid + 256 * s);
        float sr = 0.25f * (P[f] + P[FF + f] + P[2 * FF + f] + P[3 * FF + f]);
        float si = 0.25f * (P[f + 1] + P[FF + f + 1] + P[2 * FF + f + 1] + P[3 * FF + f + 1]);
        part[8] += sr * sr + si * si;
        #pragma unroll
        for (int h = 0; h < HH; h++) {
            float ur = u_halt[h * FF + f], ui = u_halt[h * FF + f + 1];
            part[2 * h]     += ur * sr + ui * si;   // conj(u)·pool
            part[2 * h + 1] += ur * si - ui * sr;
        }
    }
    __shared__ float xw[4][9];
    #pragma unroll
    for (int t = 0; t < 9; t++) {
        float r = wred(part[t]);
        if (lane == 0) xw[wid][t] = r;
    }
    __syncthreads();
    float red[9];
    #pragma unroll
    for (int t = 0; t < 9; t++) red[t] = xw[0][t] + xw[1][t] + xw[2][t] + xw[3][t];
    float ns = red[8] + EPSV;
    // head mix softmax
    float hm0 = head_mix[0], hm1 = head_mix[1], hm2 = head_mix[2], hm3 = head_mix[3];
    float hmx = fmaxf(fmaxf(hm0, hm1), fmaxf(hm2, hm3));
    float he[4] = {expf(hm0 - hmx), expf(hm1 - hmx), expf(hm2 - hmx), expf(hm3 - hmx)};
    float hsum = he[0] + he[1] + he[2] + he[3];

    float wgt[4], addc[4], newcum[4]; int newhl[4];
    int idxb = b * HH;
    #pragma unroll
    for (int h = 0; h < HH; h++) {
        float cr = red[2 * h] * norm_inv[h], ci = red[2 * h + 1] * norm_inv[h];
        float alpha = (cr * cr + ci * ci) / ns;
        float beta = 1.0f - alpha;
        float gamma = cr * cr / ns;
        float lg[3];
        #pragma unroll
        for (int j = 0; j < 3; j++)
            lg[j] = alpha * W_halt[(h * 3 + 0) * 3 + j] + beta * W_halt[(h * 3 + 1) * 3 + j] +
                    gamma * W_halt[(h * 3 + 2) * 3 + j] + b_halt[h * 3 + j];
        float mx = fmaxf(lg[0], fmaxf(lg[1], lg[2]));
        float e0 = expf(lg[0] - mx), e1 = expf(lg[1] - mx), e2 = expf(lg[2] - mx);
        float p_halt = (e0 + e1) / (e0 + e1 + e2);
        float cm = cum[idxb + h];
        int hl = halted[idxb + h];
        float would = cm + p_halt;
        int halts_now = (would >= THRESHV) || is_last;
        int active = hl ? 0 : 1;
        wgt[h]  = active ? (halts_now ? (1.0f - cm) : p_halt) : 0.0f;
        addc[h] = active ? p_halt : 0.0f;
        newcum[h] = (active && !halts_now) ? would : cm;
        newhl[h]  = hl || (active && halts_now);
    }
    __syncthreads();   // ensure every thread read cum/halted before any write
    if (tid < HH) {
        cost[idxb + tid] += addc[tid];
        cum[idxb + tid] = newcum[tid];
        halted[idxb + tid] = newhl[tid];
    }
    float hwv[4];
    #pragma unroll
    for (int h = 0; h < HH; h++) hwv[h] = (he[h] / hsum) * wgt[h];
    #pragma unroll
    for (int s = 0; s < 2; s++) {
        int f = 2 * (tid + 256 * s);
        size_t mo = (size_t)b * FF + f;
        float m0 = merged[mo], m1 = merged[mo + 1];
        #pragma unroll
        for (int h = 0; h < HH; h++) {
            m0 += hwv[h] * P[h * FF + f];
            m1 += hwv[h] * P[h * FF + f + 1];
        }
        merged[mo] = m0; merged[mo + 1] = m1;
    }
}

// ---------------- final output ----------------
__global__ void k_out(const float* __restrict__ psi, const float* __restrict__ merged,
                      const float* __restrict__ out_scale, float* __restrict__ out, int total) {
    int i = blockIdx.x * 256 + threadIdx.x;
    if (i >= total) return;
    float p = psi[i];
    out[i] = p + out_scale[0] * (merged[i] - p);
}

__global__ void k_costmean(const float* __restrict__ cost, float* __restrict__ out, int n) {
    __shared__ float red[256];
    int tid = threadIdx.x;
    float s = 0.f;
    for (int i = tid; i < n; i += 256) s += cost[i];
    red[tid] = s; __syncthreads();
    for (int off = 128; off > 0; off >>= 1) {
        if (tid < off) red[tid] += red[tid + off];
        __syncthreads();
    }
    if (tid == 0) out[0] = red[0] / (float)n;
}

extern "C" void kernel_launch(void* const* d_in, const int* in_sizes, int n_in,
                              void* d_out, int out_size, void* d_ws, size_t ws_size,
                              hipStream_t stream) {
    const float* psi       = (const float*)d_in[0];
    const float* bank_keys = (const float*)d_in[1];
    const float* bank_vals = (const float*)d_in[2];
    const float* u_halt    = (const float*)d_in[3];
    const float* W_halt    = (const float*)d_in[4];
    const float* b_halt    = (const float*)d_in[5];
    const float* head_mix  = (const float*)d_in[6];
    const float* out_scale = (const float*)d_in[7];
    float* out = (float*)d_out;

    const int BT = in_sizes[0] / FF;    // 4096

    float* ws = (float*)d_ws;
    size_t off = 0;
    float* psi_h  = ws + off; off += (size_t)BT * HH * FF;
    float* feat   = ws + off; off += (size_t)BT * FF;
    float* merged = ws + off; off += (size_t)BT * FF;     // zero region starts at merged
    float* cum    = ws + off; off += (size_t)BT * HH;
    float* costv  = ws + off; off += (size_t)BT * HH;
    int*   halted = (int*)(ws + off); off += (size_t)BT * HH;
    float* topw   = ws + off; off += (size_t)BT * HH * KK;
    int*   topi   = (int*)(ws + off); off += (size_t)BT * HH * KK;
    float* norminv = ws + off; off += 16;
    float* scores = ws + off;
    size_t fixed = off;

    size_t ws_floats = ws_size / 4;
    int RC = 1024;                               // rows per GEMM chunk
    while (RC > 64 && fixed + (size_t)RC * HH * NN > ws_floats) RC >>= 1;
    int nchunks = BT / RC;

    // init
    int tot_ph = BT * HH * FF;
    k_init_psih<<<(tot_ph + 255) / 256, 256, 0, stream>>>(psi, psi_h, tot_ph);
    hipMemsetAsync(merged, 0, ((size_t)BT * FF + 3 * (size_t)BT * HH) * sizeof(float), stream);
    k_unorm<<<1, 256, 0, stream>>>(u_halt, norminv);

    int tot_bf = BT * FF;
    for (int it = 0; it < TMAXI; ++it) {
        k_pool<<<(tot_bf + 255) / 256, 256, 0, stream>>>(psi_h, feat, tot_bf);
        for (int c = 0; c < nchunks; ++c) {
            k_gemm<<<dim3((HH * NN) / 64, RC / 64), 256, 0, stream>>>(
                feat + (size_t)c * RC * FF, bank_keys, scores);
            k_softtop<<<dim3(RC, HH), 256, 0, stream>>>(scores, topw, topi, c * RC);
        }
        k_solve<<<BT * HH, 256, 0, stream>>>(psi_h, bank_vals, topw, topi);
        k_halt<<<BT, 256, 0, stream>>>(psi_h, u_halt, norminv, W_halt, b_halt, head_mix,
                                       merged, cum, costv, halted, (it == TMAXI - 1) ? 1 : 0);
    }
    k_out<<<(tot_bf + 255) / 256, 256, 0, stream>>>(psi, merged, out_scale, out, tot_bf);
    k_costmean<<<1, 256, 0, stream>>>(costv, out + tot_bf, BT * HH);
}

// Round 2
// 1687.605 us; speedup vs baseline: 3.7480x; 3.7480x over previous
//
#include <hip/hip_runtime.h>
#include <math.h>

#define HH 4
#define DD 512
#define FF 1024          // 2*DD floats per complex vector
#define NN 2048
#define KK 4
#define TMAXI 4
#define THRESHV 0.99f
#define EPSV 1e-6f

typedef unsigned short ushort_t;
typedef __attribute__((ext_vector_type(8))) __bf16 bf16x8;
typedef __attribute__((ext_vector_type(4))) float f32x4;

__device__ __forceinline__ unsigned short f2bf(float x) {
    unsigned int u = __float_as_uint(x);
    unsigned int r = (u + 0x7FFF + ((u >> 16) & 1)) >> 16;   // round-to-nearest-even
    return (unsigned short)r;
}

typedef __attribute__((address_space(3))) unsigned int lds_u32;
typedef __attribute__((address_space(1))) const unsigned int glb_u32;
__device__ __forceinline__ void gl_lds16(const void* g, void* s) {
    __builtin_amdgcn_global_load_lds((glb_u32*)g, (lds_u32*)s, 16, 0, 0);
}

// ---------------- init: broadcast psi -> psi_h ----------------
__global__ void k_init_psih(const float* __restrict__ psi, float* __restrict__ psi_h, int total) {
    int i = blockIdx.x * 256 + threadIdx.x;
    if (i >= total) return;
    int f = i & (FF - 1);
    int b = i >> 12;               // i / (HH*FF)
    psi_h[i] = psi[(size_t)b * FF + f];
}

// ---------------- u_halt norms ----------------
__global__ void k_unorm(const float* __restrict__ u_halt, float* __restrict__ norm_inv) {
    __shared__ float red[256];
    int tid = threadIdx.x;
    for (int h = 0; h < HH; ++h) {
        float s = 0.f;
        for (int i = tid; i < FF; i += 256) { float v = u_halt[h * FF + i]; s += v * v; }
        red[tid] = s; __syncthreads();
        for (int off = 128; off > 0; off >>= 1) {
            if (tid < off) red[tid] += red[tid + off];
            __syncthreads();
        }
        if (tid == 0) norm_inv[h] = 1.0f / sqrtf(red[0] + EPSV);
        __syncthreads();
    }
}

// ---------------- fp32 -> bf16 cast (bank_keys) ----------------
__global__ void k_cvt_bf(const float* __restrict__ in, ushort_t* __restrict__ out, int total) {
    int i = blockIdx.x * 256 + threadIdx.x;
    if (i >= total) return;
    out[i] = f2bf(in[i]);
}

// ---------------- pool over heads -> feat (bf16) ----------------
__global__ void k_pool(const float* __restrict__ psi_h, ushort_t* __restrict__ feat, int total) {
    int i = blockIdx.x * 256 + threadIdx.x;
    if (i >= total) return;
    int f = i & (FF - 1); int b = i >> 10;
    const float* p = psi_h + (size_t)b * HH * FF + f;
    feat[i] = f2bf(0.25f * (p[0] + p[FF] + p[2 * FF] + p[3 * FF]));
}

// ---------------- scores GEMM (bf16 MFMA): C[r][n] = dot(A_r, B_n) ----------------
// A: RC x 1024 bf16 row-major, B: 8192 x 1024 bf16 row-major, C: RC x 8192 fp32
#define BM 128
#define BN 128
#define BKE 32   // k elems per LDS tile (64 B per row)
__global__ __launch_bounds__(256) void k_gemm_mfma(const ushort_t* __restrict__ A,
                                                   const ushort_t* __restrict__ B,
                                                   float* __restrict__ C) {
    __shared__ __align__(16) ushort_t As[BM * BKE];
    __shared__ __align__(16) ushort_t Bs[BN * BKE];
    int tid = threadIdx.x;
    int lane = tid & 63, w = tid >> 6;
    int row0 = blockIdx.y * BM, col0 = blockIdx.x * BN;

    // staging: wave w, pass p covers 16 rows; lane L -> row L>>2, 16B chunk L&3
    const ushort_t* gA = A + (size_t)(row0 + w * 16 + (lane >> 2)) * FF + (lane & 3) * 8;
    const ushort_t* gB = B + (size_t)(col0 + w * 16 + (lane >> 2)) * FF + (lane & 3) * 8;
    ushort_t* sA = As + (w * 16) * BKE;   // wave-uniform base; HW adds lane*16 B
    ushort_t* sB = Bs + (w * 16) * BKE;

    // fragment addressing: lane holds A[m=lane&15][k=(lane>>4)*8 .. +8]
    int fr = lane & 15;
    int fk = (lane >> 4) * 8;
    int wr0 = (w >> 1) * 64, wc0 = (w & 1) * 64;

    f32x4 acc[4][4] = {};

    for (int kb = 0; kb < FF; kb += BKE) {
        gl_lds16(gA + kb, sA);
        gl_lds16(gA + kb + (size_t)64 * FF, sA + 64 * BKE);
        gl_lds16(gB + kb, sB);
        gl_lds16(gB + kb + (size_t)64 * FF, sB + 64 * BKE);
        __syncthreads();   // compiler drains vmcnt before barrier
        bf16x8 af[4], bfv[4];
        #pragma unroll
        for (int i = 0; i < 4; i++) af[i] = *(const bf16x8*)&As[(wr0 + 16 * i + fr) * BKE + fk];
        #pragma unroll
        for (int j = 0; j < 4; j++) bfv[j] = *(const bf16x8*)&Bs[(wc0 + 16 * j + fr) * BKE + fk];
        #pragma unroll
        for (int i = 0; i < 4; i++)
            #pragma unroll
            for (int j = 0; j < 4; j++)
                acc[i][j] = __builtin_amdgcn_mfma_f32_16x16x32_bf16(af[i], bfv[j], acc[i][j], 0, 0, 0);
        __syncthreads();
    }

    // C/D layout: col = lane&15, row = (lane>>4)*4 + reg   [measured m89/m91]
    int crow = (lane >> 4) * 4;
    int ccol = lane & 15;
    #pragma unroll
    for (int i = 0; i < 4; i++)
        #pragma unroll
        for (int r = 0; r < 4; r++) {
            float* Cr = C + (size_t)(row0 + wr0 + 16 * i + crow + r) * (HH * NN) + col0 + wc0 + ccol;
            #pragma unroll
            for (int j = 0; j < 4; j++) Cr[16 * j] = acc[i][j][r];
        }
}

// ---------------- softmax + top-4 per (row, head) ----------------
__global__ __launch_bounds__(256) void k_softtop(const float* __restrict__ Sc,
                                                 float* __restrict__ topw, int* __restrict__ topi,
                                                 int row0) {
    int r = blockIdx.x, h = blockIdx.y;
    int tid = threadIdx.x;
    const float* S = Sc + (size_t)r * (HH * NN) + h * NN;
    float v[8];
    #pragma unroll
    for (int j = 0; j < 8; j++) v[j] = S[tid + 256 * j];
    __shared__ float rv[256];
    __shared__ int ri[256];
    float bm = v[0];
    #pragma unroll
    for (int j = 1; j < 8; j++) bm = fmaxf(bm, v[j]);
    rv[tid] = bm; __syncthreads();
    for (int off = 128; off > 0; off >>= 1) {
        if (tid < off) rv[tid] = fmaxf(rv[tid], rv[tid + off]);
        __syncthreads();
    }
    float smax = rv[0]; __syncthreads();
    float se = 0.f;
    #pragma unroll
    for (int j = 0; j < 8; j++) se += expf(v[j] - smax);
    rv[tid] = se; __syncthreads();
    for (int off = 128; off > 0; off >>= 1) {
        if (tid < off) rv[tid] += rv[tid + off];
        __syncthreads();
    }
    float Zinv = 1.0f / rv[0]; __syncthreads();
    int gbh = (row0 + r) * HH + h;
    for (int k = 0; k < KK; k++) {
        float bv = -INFINITY; int bi = NN;
        #pragma unroll
        for (int j = 0; j < 8; j++) {
            int n = tid + 256 * j;
            if (v[j] > bv) { bv = v[j]; bi = n; }
        }
        rv[tid] = bv; ri[tid] = bi; __syncthreads();
        for (int off = 128; off > 0; off >>= 1) {
            if (tid < off) {
                float ov = rv[tid + off]; int oi = ri[tid + off];
                if (ov > rv[tid] || (ov == rv[tid] && oi < ri[tid])) { rv[tid] = ov; ri[tid] = oi; }
            }
            __syncthreads();
        }
        float wv = rv[0]; int wi = ri[0]; __syncthreads();
        if (tid == (wi & 255)) v[wi >> 8] = -INFINITY;
        if (tid == 0) { topw[gbh * KK + k] = expf(wv - smax) * Zinv; topi[gbh * KK + k] = wi; }
    }
}

// ---------------- wave reduce ----------------
__device__ inline float wred(float v) {
    #pragma unroll
    for (int m = 1; m < 64; m <<= 1) v += __shfl_xor(v, m, 64);
    return v;
}

// ---------------- projection + normalize (psi_h updated in place) ----------------
__global__ __launch_bounds__(256) void k_solve(float* __restrict__ psi_h,
                                               const float* __restrict__ bank_vals,
                                               const float* __restrict__ topw,
                                               const int* __restrict__ topi) {
    int bh = blockIdx.x;
    int h = bh & (HH - 1);
    int tid = threadIdx.x;
    int wid = tid >> 6, lane = tid & 63;
    float w[KK]; int ix[KK];
    #pragma unroll
    for (int k = 0; k < KK; k++) { w[k] = topw[bh * KK + k]; ix[k] = topi[bh * KK + k]; }
    float* P = psi_h + (size_t)bh * FF;
    float pr[2], pim[2], Ur[KK][2], Ui[KK][2];
    #pragma unroll
    for (int s = 0; s < 2; s++) {
        int d = tid + 256 * s;
        pr[s] = P[2 * d]; pim[s] = P[2 * d + 1];
        #pragma unroll
        for (int k = 0; k < KK; k++) {
            const float* Vp = bank_vals + ((size_t)h * NN + ix[k]) * FF;
            Ur[k][s] = Vp[2 * d] * w[k];
            Ui[k][s] = Vp[2 * d + 1] * w[k];
        }
    }
    float part[28];
    #pragma unroll
    for (int t = 0; t < 28; t++) part[t] = 0.f;
    #pragma unroll
    for (int s = 0; s < 2; s++) {
        #pragma unroll
        for (int k = 0; k < KK; k++) {
            part[2 * k]     += Ur[k][s] * pr[s] + Ui[k][s] * pim[s];
            part[2 * k + 1] += Ur[k][s] * pim[s] - Ui[k][s] * pr[s];
        }
        int t = 8;
        #pragma unroll
        for (int k = 0; k < KK; k++)
            #pragma unroll
            for (int j = k; j < KK; j++) {
                part[t]     += Ur[k][s] * Ur[j][s] + Ui[k][s] * Ui[j][s];
                part[t + 1] += Ur[k][s] * Ui[j][s] - Ui[k][s] * Ur[j][s];
                t += 2;
            }
    }
    __shared__ float xw[4][28];
    #pragma unroll
    for (int t = 0; t < 28; t++) {
        float r = wred(part[t]);
        if (lane == 0) xw[wid][t] = r;
    }
    __syncthreads();
    float red[28];
    #pragma unroll
    for (int t = 0; t < 28; t++) red[t] = xw[0][t] + xw[1][t] + xw[2][t] + xw[3][t];

    float mr[KK], mi[KK], Gr[KK][KK], Gi[KK][KK];
    #pragma unroll
    for (int k = 0; k < KK; k++) { mr[k] = red[2 * k]; mi[k] = red[2 * k + 1]; }
    {
        int t = 8;
        #pragma unroll
        for (int k = 0; k < KK; k++)
            #pragma unroll
            for (int j = k; j < KK; j++) {
                Gr[k][j] = red[t]; Gi[k][j] = red[t + 1];
                if (j > k) { Gr[j][k] = red[t]; Gi[j][k] = -red[t + 1]; }
                t += 2;
            }
    }
    #pragma unroll
    for (int k = 0; k < KK; k++) { Gr[k][k] += EPSV; Gi[k][k] = 0.f; }

    float Lr[KK][KK], Li[KK][KK];
    #pragma unroll
    for (int j = 0; j < KK; j++) {
        float s = Gr[j][j];
        #pragma unroll
        for (int p = 0; p < KK; p++) if (p < j) s -= Lr[j][p] * Lr[j][p] + Li[j][p] * Li[j][p];
        float ljj = sqrtf(fmaxf(s, 1e-30f));
        Lr[j][j] = ljj; Li[j][j] = 0.f;
        float inv = 1.0f / ljj;
        #pragma unroll
        for (int k = 0; k < KK; k++) {
            if (k > j) {
                float ar = Gr[k][j], ai = Gi[k][j];
                #pragma unroll
                for (int p = 0; p < KK; p++) if (p < j) {
                    ar -= Lr[k][p] * Lr[j][p] + Li[k][p] * Li[j][p];
                    ai -= Li[k][p] * Lr[j][p] - Lr[k][p] * Li[j][p];
                }
                Lr[k][j] = ar * inv; Li[k][j] = ai * inv;
            }
        }
    }
    float yr[KK], yi[KK];
    #pragma unroll
    for (int j = 0; j < KK; j++) {
        float ar = mr[j], ai = mi[j];
        #pragma unroll
        for (int p = 0; p < KK; p++) if (p < j) {
            ar -= Lr[j][p] * yr[p] - Li[j][p] * yi[p];
            ai -= Lr[j][p] * yi[p] + Li[j][p] * yr[p];
        }
        float inv = 1.0f / Lr[j][j];
        yr[j] = ar * inv; yi[j] = ai * inv;
    }
    float xr[KK], xi2[KK];
    #pragma unroll
    for (int j = KK - 1; j >= 0; j--) {
        float ar = yr[j], ai = yi[j];
        #pragma unroll
        for (int p = 0; p < KK; p++) if (p > j) {
            ar -= Lr[p][j] * xr[p] + Li[p][j] * xi2[p];
            ai -= Lr[p][j] * xi2[p] - Li[p][j] * xr[p];
        }
        float inv = 1.0f / Lr[j][j];
        xr[j] = ar * inv; xi2[j] = ai * inv;
    }
    float pjr[2], pji[2];
    float sqp = 0.f;
    #pragma unroll
    for (int s = 0; s < 2; s++) {
        float ar = 0.f, ai = 0.f;
        #pragma unroll
        for (int k = 0; k < KK; k++) {
            ar += Ur[k][s] * xr[k] - Ui[k][s] * xi2[k];
            ai += Ur[k][s] * xi2[k] + Ui[k][s] * xr[k];
        }
        pjr[s] = ar; pji[s] = ai;
        sqp += ar * ar + ai * ai;
    }
    float rs = wred(sqp);
    __syncthreads();
    if (lane == 0) xw[wid][0] = rs;
    __syncthreads();
    float sq = xw[0][0] + xw[1][0] + xw[2][0] + xw[3][0];
    float rn = 1.0f / sqrtf(fmaxf(sq, 1e-6f));
    #pragma unroll
    for (int s = 0; s < 2; s++) {
        int d = tid + 256 * s;
        P[2 * d] = pjr[s] * rn;
        P[2 * d + 1] = pji[s] * rn;
    }
}

// ---------------- halting + merged accumulation ----------------
__global__ __launch_bounds__(256) void k_halt(const float* __restrict__ psi_h,
                                              const float* __restrict__ u_halt,
                                              const float* __restrict__ norm_inv,
                                              const float* __restrict__ W_halt,
                                              const float* __restrict__ b_halt,
                                              const float* __restrict__ head_mix,
                                              float* __restrict__ merged,
                                              float* __restrict__ cum,
                                              float* __restrict__ cost,
                                              int* __restrict__ halted,
                                              int is_last) {
    int b = blockIdx.x; int tid = threadIdx.x;
    int wid = tid >> 6, lane = tid & 63;
    const float* P = psi_h + (size_t)b * HH * FF;
    float part[9];
    #pragma unroll
    for (int t = 0; t < 9; t++) part[t] = 0.f;
    #pragma unroll
    for (int s = 0; s < 2; s++) {
        int f = 2 * (tid + 256 * s);
        float sr = 0.25f * (P[f] + P[FF + f] + P[2 * FF + f] + P[3 * FF + f]);
        float si = 0.25f * (P[f + 1] + P[FF + f + 1] + P[2 * FF + f + 1] + P[3 * FF + f + 1]);
        part[8] += sr * sr + si * si;
        #pragma unroll
        for (int h = 0; h < HH; h++) {
            float ur = u_halt[h * FF + f], ui = u_halt[h * FF + f + 1];
            part[2 * h]     += ur * sr + ui * si;
            part[2 * h + 1] += ur * si - ui * sr;
        }
    }
    __shared__ float xw[4][9];
    #pragma unroll
    for (int t = 0; t < 9; t++) {
        float r = wred(part[t]);
        if (lane == 0) xw[wid][t] = r;
    }
    __syncthreads();
    float red[9];
    #pragma unroll
    for (int t = 0; t < 9; t++) red[t] = xw[0][t] + xw[1][t] + xw[2][t] + xw[3][t];
    float ns = red[8] + EPSV;
    float hm0 = head_mix[0], hm1 = head_mix[1], hm2 = head_mix[2], hm3 = head_mix[3];
    float hmx = fmaxf(fmaxf(hm0, hm1), fmaxf(hm2, hm3));
    float he[4] = {expf(hm0 - hmx), expf(hm1 - hmx), expf(hm2 - hmx), expf(hm3 - hmx)};
    float hsum = he[0] + he[1] + he[2] + he[3];

    float wgt[4], addc[4], newcum[4]; int newhl[4];
    int idxb = b * HH;
    #pragma unroll
    for (int h = 0; h < HH; h++) {
        float cr = red[2 * h] * norm_inv[h], ci = red[2 * h + 1] * norm_inv[h];
        float alpha = (cr * cr + ci * ci) / ns;
        float beta = 1.0f - alpha;
        float gamma = cr * cr / ns;
        float lg[3];
        #pragma unroll
        for (int j = 0; j < 3; j++)
            lg[j] = alpha * W_halt[(h * 3 + 0) * 3 + j] + beta * W_halt[(h * 3 + 1) * 3 + j] +
                    gamma * W_halt[(h * 3 + 2) * 3 + j] + b_halt[h * 3 + j];
        float mx = fmaxf(lg[0], fmaxf(lg[1], lg[2]));
        float e0 = expf(lg[0] - mx), e1 = expf(lg[1] - mx), e2 = expf(lg[2] - mx);
        float p_halt = (e0 + e1) / (e0 + e1 + e2);
        float cm = cum[idxb + h];
        int hl = halted[idxb + h];
        float would = cm + p_halt;
        int halts_now = (would >= THRESHV) || is_last;
        int active = hl ? 0 : 1;
        wgt[h]  = active ? (halts_now ? (1.0f - cm) : p_halt) : 0.0f;
        addc[h] = active ? p_halt : 0.0f;
        newcum[h] = (active && !halts_now) ? would : cm;
        newhl[h]  = hl || (active && halts_now);
    }
    __syncthreads();
    if (tid < HH) {
        cost[idxb + tid] += addc[tid];
        cum[idxb + tid] = newcum[tid];
        halted[idxb + tid] = newhl[tid];
    }
    float hwv[4];
    #pragma unroll
    for (int h = 0; h < HH; h++) hwv[h] = (he[h] / hsum) * wgt[h];
    #pragma unroll
    for (int s = 0; s < 2; s++) {
        int f = 2 * (tid + 256 * s);
        size_t mo = (size_t)b * FF + f;
        float m0 = merged[mo], m1 = merged[mo + 1];
        #pragma unroll
        for (int h = 0; h < HH; h++) {
            m0 += hwv[h] * P[h * FF + f];
            m1 += hwv[h] * P[h * FF + f + 1];
        }
        merged[mo] = m0; merged[mo + 1] = m1;
    }
}

// ---------------- final output ----------------
__global__ void k_out(const float* __restrict__ psi, const float* __restrict__ merged,
                      const float* __restrict__ out_scale, float* __restrict__ out, int total) {
    int i = blockIdx.x * 256 + threadIdx.x;
    if (i >= total) return;
    float p = psi[i];
    out[i] = p + out_scale[0] * (merged[i] - p);
}

__global__ void k_costmean(const float* __restrict__ cost, float* __restrict__ out, int n) {
    __shared__ float red[256];
    int tid = threadIdx.x;
    float s = 0.f;
    for (int i = tid; i < n; i += 256) s += cost[i];
    red[tid] = s; __syncthreads();
    for (int off = 128; off > 0; off >>= 1) {
        if (tid < off) red[tid] += red[tid + off];
        __syncthreads();
    }
    if (tid == 0) out[0] = red[0] / (float)n;
}

extern "C" void kernel_launch(void* const* d_in, const int* in_sizes, int n_in,
                              void* d_out, int out_size, void* d_ws, size_t ws_size,
                              hipStream_t stream) {
    const float* psi       = (const float*)d_in[0];
    const float* bank_keys = (const float*)d_in[1];
    const float* bank_vals = (const float*)d_in[2];
    const float* u_halt    = (const float*)d_in[3];
    const float* W_halt    = (const float*)d_in[4];
    const float* b_halt    = (const float*)d_in[5];
    const float* head_mix  = (const float*)d_in[6];
    const float* out_scale = (const float*)d_in[7];
    float* out = (float*)d_out;

    const int BT = in_sizes[0] / FF;    // 4096

    float* ws = (float*)d_ws;
    size_t off = 0;
    float* psi_h  = ws + off; off += (size_t)BT * HH * FF;
    float* merged = ws + off; off += (size_t)BT * FF;     // zero region starts at merged
    float* cum    = ws + off; off += (size_t)BT * HH;
    float* costv  = ws + off; off += (size_t)BT * HH;
    int*   halted = (int*)(ws + off); off += (size_t)BT * HH;
    float* topw   = ws + off; off += (size_t)BT * HH * KK;
    int*   topi   = (int*)(ws + off); off += (size_t)BT * HH * KK;
    float* norminv = ws + off; off += 16;
    ushort_t* feat_bf = (ushort_t*)(ws + off); off += (size_t)BT * FF / 2;
    ushort_t* keys_bf = (ushort_t*)(ws + off); off += (size_t)HH * NN * FF / 2;
    float* scores = ws + off;
    size_t fixed = off;

    size_t ws_floats = ws_size / 4;
    int RC = BT;                                 // rows per GEMM chunk
    while (RC > 128 && fixed + (size_t)RC * HH * NN > ws_floats) RC >>= 1;
    int nchunks = BT / RC;

    // init
    int tot_ph = BT * HH * FF;
    k_init_psih<<<(tot_ph + 255) / 256, 256, 0, stream>>>(psi, psi_h, tot_ph);
    hipMemsetAsync(merged, 0, ((size_t)BT * FF + 3 * (size_t)BT * HH) * sizeof(float), stream);
    k_unorm<<<1, 256, 0, stream>>>(u_halt, norminv);
    int tot_keys = HH * NN * FF;
    k_cvt_bf<<<(tot_keys + 255) / 256, 256, 0, stream>>>(bank_keys, keys_bf, tot_keys);

    int tot_bf = BT * FF;
    for (int it = 0; it < TMAXI; ++it) {
        k_pool<<<(tot_bf + 255) / 256, 256, 0, stream>>>(psi_h, feat_bf, tot_bf);
        for (int c = 0; c < nchunks; ++c) {
            k_gemm_mfma<<<dim3((HH * NN) / BN, RC / BM), 256, 0, stream>>>(
                feat_bf + (size_t)c * RC * FF, keys_bf, scores);
            k_softtop<<<dim3(RC, HH), 256, 0, stream>>>(scores, topw, topi, c * RC);
        }
        k_solve<<<BT * HH, 256, 0, stream>>>(psi_h, bank_vals, topw, topi);
        k_halt<<<BT, 256, 0, stream>>>(psi_h, u_halt, norminv, W_halt, b_halt, head_mix,
                                       merged, cum, costv, halted, (it == TMAXI - 1) ? 1 : 0);
    }
    k_out<<<(tot_bf + 255) / 256, 256, 0, stream>>>(psi, merged, out_scale, out, tot_bf);
    k_costmean<<<1, 256, 0, stream>>>(costv, out + tot_bf, BT * HH);
}

// Round 3
// 1349.328 us; speedup vs baseline: 4.6877x; 1.2507x over previous
//
#include <hip/hip_runtime.h>
#include <math.h>

#define HH 4
#define DD 512
#define FF 1024          // 2*DD floats per complex vector
#define NN 2048
#define KK 4
#define TMAXI 4
#define THRESHV 0.99f
#define EPSV 1e-6f

typedef unsigned short ushort_t;
typedef __attribute__((ext_vector_type(8))) __bf16 bf16x8;
typedef __attribute__((ext_vector_type(4))) float f32x4;
typedef __attribute__((ext_vector_type(4))) unsigned short us4;

__device__ __forceinline__ unsigned short f2bf(float x) {
    unsigned int u = __float_as_uint(x);
    unsigned int r = (u + 0x7FFF + ((u >> 16) & 1)) >> 16;   // round-to-nearest-even
    return (unsigned short)r;
}

typedef __attribute__((address_space(3))) unsigned int lds_u32;
typedef __attribute__((address_space(1))) const unsigned int glb_u32;
__device__ __forceinline__ void gl_lds16(const void* g, void* s) {
    __builtin_amdgcn_global_load_lds((glb_u32*)g, (lds_u32*)s, 16, 0, 0);
}

// ---------------- u_halt norms ----------------
__global__ void k_unorm(const float* __restrict__ u_halt, float* __restrict__ norm_inv) {
    __shared__ float red[256];
    int tid = threadIdx.x;
    for (int h = 0; h < HH; ++h) {
        float s = 0.f;
        for (int i = tid; i < FF; i += 256) { float v = u_halt[h * FF + i]; s += v * v; }
        red[tid] = s; __syncthreads();
        for (int off = 128; off > 0; off >>= 1) {
            if (tid < off) red[tid] += red[tid + off];
            __syncthreads();
        }
        if (tid == 0) norm_inv[h] = 1.0f / sqrtf(red[0] + EPSV);
        __syncthreads();
    }
}

// ---------------- fp32 -> bf16 cast ----------------
__global__ void k_cvt_bf(const float* __restrict__ in, ushort_t* __restrict__ out, int total) {
    int i = blockIdx.x * 256 + threadIdx.x;
    if (i >= total) return;
    out[i] = f2bf(in[i]);
}

// ---------------- scores GEMM (bf16 MFMA) ----------------
#define BM 128
#define BN 128
#define BKE 32
__global__ __launch_bounds__(256) void k_gemm_mfma(const ushort_t* __restrict__ A,
                                                   const ushort_t* __restrict__ B,
                                                   float* __restrict__ C) {
    __shared__ __align__(16) ushort_t As[BM * BKE];
    __shared__ __align__(16) ushort_t Bs[BN * BKE];
    int tid = threadIdx.x;
    int lane = tid & 63, w = tid >> 6;
    int row0 = blockIdx.y * BM, col0 = blockIdx.x * BN;

    const ushort_t* gA = A + (size_t)(row0 + w * 16 + (lane >> 2)) * FF + (lane & 3) * 8;
    const ushort_t* gB = B + (size_t)(col0 + w * 16 + (lane >> 2)) * FF + (lane & 3) * 8;
    ushort_t* sA = As + (w * 16) * BKE;
    ushort_t* sB = Bs + (w * 16) * BKE;

    int fr = lane & 15;
    int fk = (lane >> 4) * 8;
    int wr0 = (w >> 1) * 64, wc0 = (w & 1) * 64;

    f32x4 acc[4][4] = {};

    for (int kb = 0; kb < FF; kb += BKE) {
        gl_lds16(gA + kb, sA);
        gl_lds16(gA + kb + (size_t)64 * FF, sA + 64 * BKE);
        gl_lds16(gB + kb, sB);
        gl_lds16(gB + kb + (size_t)64 * FF, sB + 64 * BKE);
        __syncthreads();
        bf16x8 af[4], bfv[4];
        #pragma unroll
        for (int i = 0; i < 4; i++) af[i] = *(const bf16x8*)&As[(wr0 + 16 * i + fr) * BKE + fk];
        #pragma unroll
        for (int j = 0; j < 4; j++) bfv[j] = *(const bf16x8*)&Bs[(wc0 + 16 * j + fr) * BKE + fk];
        #pragma unroll
        for (int i = 0; i < 4; i++)
            #pragma unroll
            for (int j = 0; j < 4; j++)
                acc[i][j] = __builtin_amdgcn_mfma_f32_16x16x32_bf16(af[i], bfv[j], acc[i][j], 0, 0, 0);
        __syncthreads();
    }

    int crow = (lane >> 4) * 4;
    int ccol = lane & 15;
    #pragma unroll
    for (int i = 0; i < 4; i++)
        #pragma unroll
        for (int r = 0; r < 4; r++) {
            float* Cr = C + (size_t)(row0 + wr0 + 16 * i + crow + r) * (HH * NN) + col0 + wc0 + ccol;
            #pragma unroll
            for (int j = 0; j < 4; j++) Cr[16 * j] = acc[i][j][r];
        }
}

// ---------------- softmax + top-4 per (row, head) ----------------
__global__ __launch_bounds__(256) void k_softtop(const float* __restrict__ Sc,
                                                 float* __restrict__ topw, int* __restrict__ topi,
                                                 int row0) {
    int r = blockIdx.x, h = blockIdx.y;
    int tid = threadIdx.x;
    const float* S = Sc + (size_t)r * (HH * NN) + h * NN;
    float v[8];
    #pragma unroll
    for (int j = 0; j < 8; j++) v[j] = S[tid + 256 * j];
    __shared__ float rv[256];
    __shared__ int ri[256];
    float bm = v[0];
    #pragma unroll
    for (int j = 1; j < 8; j++) bm = fmaxf(bm, v[j]);
    rv[tid] = bm; __syncthreads();
    for (int off = 128; off > 0; off >>= 1) {
        if (tid < off) rv[tid] = fmaxf(rv[tid], rv[tid + off]);
        __syncthreads();
    }
    float smax = rv[0]; __syncthreads();
    float se = 0.f;
    #pragma unroll
    for (int j = 0; j < 8; j++) se += expf(v[j] - smax);
    rv[tid] = se; __syncthreads();
    for (int off = 128; off > 0; off >>= 1) {
        if (tid < off) rv[tid] += rv[tid + off];
        __syncthreads();
    }
    float Zinv = 1.0f / rv[0]; __syncthreads();
    int gbh = (row0 + r) * HH + h;
    for (int k = 0; k < KK; k++) {
        float bv = -INFINITY; int bi = NN;
        #pragma unroll
        for (int j = 0; j < 8; j++) {
            int n = tid + 256 * j;
            if (v[j] > bv) { bv = v[j]; bi = n; }
        }
        rv[tid] = bv; ri[tid] = bi; __syncthreads();
        for (int off = 128; off > 0; off >>= 1) {
            if (tid < off) {
                float ov = rv[tid + off]; int oi = ri[tid + off];
                if (ov > rv[tid] || (ov == rv[tid] && oi < ri[tid])) { rv[tid] = ov; ri[tid] = oi; }
            }
            __syncthreads();
        }
        float wv = rv[0]; int wi = ri[0]; __syncthreads();
        if (tid == (wi & 255)) v[wi >> 8] = -INFINITY;
        if (tid == 0) { topw[gbh * KK + k] = expf(wv - smax) * Zinv; topi[gbh * KK + k] = wi; }
    }
}

// ---------------- fused solve + halt + pool ----------------
// block = token b; wave w = head h; lane owns 8 complex elems.
__global__ __launch_bounds__(256) void k_fused(const float* __restrict__ psi,
                                               float* __restrict__ psi_h,
                                               const float* __restrict__ bank_vals,
                                               const float* __restrict__ topw,
                                               const int* __restrict__ topi,
                                               const float* __restrict__ u_halt,
                                               const float* __restrict__ norm_inv,
                                               const float* __restrict__ W_halt,
                                               const float* __restrict__ b_halt,
                                               const float* __restrict__ head_mix,
                                               float* __restrict__ merged,
                                               ushort_t* __restrict__ feat,
                                               float* __restrict__ cum,
                                               float* __restrict__ cost,
                                               int* __restrict__ halted,
                                               int first, int is_last) {
    __shared__ float Pn[HH][FF];     // psi_next staging (16 KB)
    __shared__ float xw[4][9];
    int b = blockIdx.x;
    int tid = threadIdx.x;
    int w = tid >> 6, lane = tid & 63;
    int bh = b * HH + w;

    float wk[KK]; int ix[KK];
    #pragma unroll
    for (int k = 0; k < KK; k++) { wk[k] = topw[bh * KK + k]; ix[k] = topi[bh * KK + k]; }

    const float* Pr = first ? (psi + (size_t)b * FF) : (psi_h + (size_t)bh * FF);
    float4 p4[4], v4[KK][4];
    #pragma unroll
    for (int c = 0; c < 4; c++) p4[c] = *(const float4*)(Pr + lane * 16 + 4 * c);
    #pragma unroll
    for (int k = 0; k < KK; k++) {
        const float* Vp = bank_vals + ((size_t)(w * NN) + ix[k]) * FF + lane * 16;
        #pragma unroll
        for (int c = 0; c < 4; c++) v4[k][c] = *(const float4*)(Vp + 4 * c);
    }

    // partials: m (8), G diag real (4), G offdiag (12) -> 24, all on RAW bank vecs
    float part[24];
    #pragma unroll
    for (int t = 0; t < 24; t++) part[t] = 0.f;
    #pragma unroll
    for (int c = 0; c < 4; c++) {
        #pragma unroll
        for (int e = 0; e < 2; e++) {
            float prr = e ? p4[c].z : p4[c].x;
            float pii = e ? p4[c].w : p4[c].y;
            float vr[KK], vi[KK];
            #pragma unroll
            for (int k = 0; k < KK; k++) {
                vr[k] = e ? v4[k][c].z : v4[k][c].x;
                vi[k] = e ? v4[k][c].w : v4[k][c].y;
            }
            #pragma unroll
            for (int k = 0; k < KK; k++) {
                part[2 * k]     += vr[k] * prr + vi[k] * pii;   // conj(v)·psi
                part[2 * k + 1] += vr[k] * pii - vi[k] * prr;
                part[8 + k]     += vr[k] * vr[k] + vi[k] * vi[k];
            }
            int t = 12;
            #pragma unroll
            for (int k = 0; k < KK; k++)
                #pragma unroll
                for (int j = k + 1; j < KK; j++) {
                    part[t]     += vr[k] * vr[j] + vi[k] * vi[j];
                    part[t + 1] += vr[k] * vi[j] - vi[k] * vr[j];
                    t += 2;
                }
        }
    }
    // wave butterfly reduce (one wave == one (b,h), so this is the full sum)
    #pragma unroll
    for (int m = 1; m < 64; m <<= 1)
        #pragma unroll
        for (int t = 0; t < 24; t++) part[t] += __shfl_xor(part[t], m, 64);

    // scale by top-k weights: G = D G'' D, m = D m''
    float mr[KK], mi[KK], Gr[KK][KK], Gi[KK][KK];
    #pragma unroll
    for (int k = 0; k < KK; k++) {
        mr[k] = part[2 * k] * wk[k];
        mi[k] = part[2 * k + 1] * wk[k];
        Gr[k][k] = part[8 + k] * wk[k] * wk[k] + EPSV;
        Gi[k][k] = 0.f;
    }
    {
        int t = 12;
        #pragma unroll
        for (int k = 0; k < KK; k++)
            #pragma unroll
            for (int j = k + 1; j < KK; j++) {
                float s = wk[k] * wk[j];
                Gr[k][j] = part[t] * s;  Gi[k][j] = part[t + 1] * s;
                Gr[j][k] = Gr[k][j];     Gi[j][k] = -Gi[k][j];
                t += 2;
            }
    }

    // complex Cholesky G = L L^H  (redundant per lane — 4x4, cheap)
    float Lr[KK][KK], Li[KK][KK];
    #pragma unroll
    for (int j = 0; j < KK; j++) {
        float s = Gr[j][j];
        #pragma unroll
        for (int p = 0; p < KK; p++) if (p < j) s -= Lr[j][p] * Lr[j][p] + Li[j][p] * Li[j][p];
        float ljj = sqrtf(fmaxf(s, 1e-30f));
        Lr[j][j] = ljj; Li[j][j] = 0.f;
        float inv = 1.0f / ljj;
        #pragma unroll
        for (int k = 0; k < KK; k++) {
            if (k > j) {
                float ar = Gr[k][j], ai = Gi[k][j];
                #pragma unroll
                for (int p = 0; p < KK; p++) if (p < j) {
                    ar -= Lr[k][p] * Lr[j][p] + Li[k][p] * Li[j][p];
                    ai -= Li[k][p] * Lr[j][p] - Lr[k][p] * Li[j][p];
                }
                Lr[k][j] = ar * inv; Li[k][j] = ai * inv;
            }
        }
    }
    float yr[KK], yi[KK];
    #pragma unroll
    for (int j = 0; j < KK; j++) {
        float ar = mr[j], ai = mi[j];
        #pragma unroll
        for (int p = 0; p < KK; p++) if (p < j) {
            ar -= Lr[j][p] * yr[p] - Li[j][p] * yi[p];
            ai -= Lr[j][p] * yi[p] + Li[j][p] * yr[p];
        }
        float inv = 1.0f / Lr[j][j];
        yr[j] = ar * inv; yi[j] = ai * inv;
    }
    float xr[KK], xi2[KK];
    #pragma unroll
    for (int j = KK - 1; j >= 0; j--) {
        float ar = yr[j], ai = yi[j];
        #pragma unroll
        for (int p = 0; p < KK; p++) if (p > j) {
            ar -= Lr[p][j] * xr[p] + Li[p][j] * xi2[p];
            ai -= Lr[p][j] * xi2[p] - Li[p][j] * xr[p];
        }
        float inv = 1.0f / Lr[j][j];
        xr[j] = ar * inv; xi2[j] = ai * inv;
    }
    // fold weights into coeff: proj = sum_k v_k * (w_k x_k)
    float cxr[KK], cxi[KK];
    #pragma unroll
    for (int k = 0; k < KK; k++) { cxr[k] = xr[k] * wk[k]; cxi[k] = xi2[k] * wk[k]; }

    float4 pj[4];
    float sqp = 0.f;
    #pragma unroll
    for (int c = 0; c < 4; c++) {
        float ar0 = 0.f, ai0 = 0.f, ar1 = 0.f, ai1 = 0.f;
        #pragma unroll
        for (int k = 0; k < KK; k++) {
            ar0 += v4[k][c].x * cxr[k] - v4[k][c].y * cxi[k];
            ai0 += v4[k][c].x * cxi[k] + v4[k][c].y * cxr[k];
            ar1 += v4[k][c].z * cxr[k] - v4[k][c].w * cxi[k];
            ai1 += v4[k][c].z * cxi[k] + v4[k][c].w * cxr[k];
        }
        pj[c].x = ar0; pj[c].y = ai0; pj[c].z = ar1; pj[c].w = ai1;
        sqp += ar0 * ar0 + ai0 * ai0 + ar1 * ar1 + ai1 * ai1;
    }
    #pragma unroll
    for (int m = 1; m < 64; m <<= 1) sqp += __shfl_xor(sqp, m, 64);
    float rn = 1.0f / sqrtf(fmaxf(sqp, 1e-6f));

    float* Pdst = psi_h + (size_t)bh * FF + lane * 16;
    #pragma unroll
    for (int c = 0; c < 4; c++) {
        float4 o; o.x = pj[c].x * rn; o.y = pj[c].y * rn; o.z = pj[c].z * rn; o.w = pj[c].w * rn;
        *(float4*)(Pdst + 4 * c) = o;
        *(float4*)&Pn[w][lane * 16 + 4 * c] = o;
    }
    __syncthreads();

    // ---------- halt phase: thread t owns floats 4t..4t+3 (2 complex) ----------
    int t4 = tid * 4;
    float4 a0 = *(const float4*)&Pn[0][t4];
    float4 a1 = *(const float4*)&Pn[1][t4];
    float4 a2 = *(const float4*)&Pn[2][t4];
    float4 a3 = *(const float4*)&Pn[3][t4];
    float4 pool;
    pool.x = 0.25f * (a0.x + a1.x + a2.x + a3.x);
    pool.y = 0.25f * (a0.y + a1.y + a2.y + a3.y);
    pool.z = 0.25f * (a0.z + a1.z + a2.z + a3.z);
    pool.w = 0.25f * (a0.w + a1.w + a2.w + a3.w);

    float pt[9];
    #pragma unroll
    for (int h = 0; h < HH; h++) {
        float4 u = *(const float4*)&u_halt[h * FF + t4];
        pt[2 * h]     = u.x * pool.x + u.y * pool.y + u.z * pool.z + u.w * pool.w;
        pt[2 * h + 1] = u.x * pool.y - u.y * pool.x + u.z * pool.w - u.w * pool.z;
    }
    pt[8] = pool.x * pool.x + pool.y * pool.y + pool.z * pool.z + pool.w * pool.w;
    #pragma unroll
    for (int m = 1; m < 64; m <<= 1)
        #pragma unroll
        for (int t = 0; t < 9; t++) pt[t] += __shfl_xor(pt[t], m, 64);
    if (lane == 0) {
        #pragma unroll
        for (int t = 0; t < 9; t++) xw[w][t] = pt[t];
    }
    __syncthreads();
    float red[9];
    #pragma unroll
    for (int t = 0; t < 9; t++) red[t] = xw[0][t] + xw[1][t] + xw[2][t] + xw[3][t];
    float ns = red[8] + EPSV;

    float hm0 = head_mix[0], hm1 = head_mix[1], hm2 = head_mix[2], hm3 = head_mix[3];
    float hmx = fmaxf(fmaxf(hm0, hm1), fmaxf(hm2, hm3));
    float he[4] = {expf(hm0 - hmx), expf(hm1 - hmx), expf(hm2 - hmx), expf(hm3 - hmx)};
    float hsum = he[0] + he[1] + he[2] + he[3];

    float wgt[4], addc[4], newcum[4]; int newhl[4];
    int idxb = b * HH;
    #pragma unroll
    for (int h = 0; h < HH; h++) {
        float cr = red[2 * h] * norm_inv[h], ci = red[2 * h + 1] * norm_inv[h];
        float alpha = (cr * cr + ci * ci) / ns;
        float beta = 1.0f - alpha;
        float gamma = cr * cr / ns;
        float lg[3];
        #pragma unroll
        for (int j = 0; j < 3; j++)
            lg[j] = alpha * W_halt[(h * 3 + 0) * 3 + j] + beta * W_halt[(h * 3 + 1) * 3 + j] +
                    gamma * W_halt[(h * 3 + 2) * 3 + j] + b_halt[h * 3 + j];
        float mx = fmaxf(lg[0], fmaxf(lg[1], lg[2]));
        float e0 = expf(lg[0] - mx), e1 = expf(lg[1] - mx), e2 = expf(lg[2] - mx);
        float p_halt = (e0 + e1) / (e0 + e1 + e2);
        float cm = cum[idxb + h];
        int hl = halted[idxb + h];
        float would = cm + p_halt;
        int halts_now = (would >= THRESHV) || is_last;
        int active = hl ? 0 : 1;
        wgt[h]  = active ? (halts_now ? (1.0f - cm) : p_halt) : 0.0f;
        addc[h] = active ? p_halt : 0.0f;
        newcum[h] = (active && !halts_now) ? would : cm;
        newhl[h]  = hl || (active && halts_now);
    }
    __syncthreads();   // all threads read cum/halted before update
    if (tid < HH) {
        cost[idxb + tid] += addc[tid];
        cum[idxb + tid] = newcum[tid];
        halted[idxb + tid] = newhl[tid];
    }
    float hwv[4];
    #pragma unroll
    for (int h = 0; h < HH; h++) hwv[h] = (he[h] / hsum) * wgt[h];

    size_t mo = (size_t)b * FF + t4;
    float4 m4 = *(const float4*)&merged[mo];
    m4.x += hwv[0] * a0.x + hwv[1] * a1.x + hwv[2] * a2.x + hwv[3] * a3.x;
    m4.y += hwv[0] * a0.y + hwv[1] * a1.y + hwv[2] * a2.y + hwv[3] * a3.y;
    m4.z += hwv[0] * a0.z + hwv[1] * a1.z + hwv[2] * a2.z + hwv[3] * a3.z;
    m4.w += hwv[0] * a0.w + hwv[1] * a1.w + hwv[2] * a2.w + hwv[3] * a3.w;
    *(float4*)&merged[mo] = m4;

    // feat for next iteration's GEMM = pooled psi_next, bf16
    us4 fb;
    fb.x = f2bf(pool.x); fb.y = f2bf(pool.y); fb.z = f2bf(pool.z); fb.w = f2bf(pool.w);
    *(us4*)&feat[mo] = fb;
}

// ---------------- final output ----------------
__global__ void k_out(const float* __restrict__ psi, const float* __restrict__ merged,
                      const float* __restrict__ out_scale, float* __restrict__ out, int total) {
    int i = blockIdx.x * 256 + threadIdx.x;
    if (i >= total) return;
    float p = psi[i];
    out[i] = p + out_scale[0] * (merged[i] - p);
}

__global__ void k_costmean(const float* __restrict__ cost, float* __restrict__ out, int n) {
    __shared__ float red[256];
    int tid = threadIdx.x;
    float s = 0.f;
    for (int i = tid; i < n; i += 256) s += cost[i];
    red[tid] = s; __syncthreads();
    for (int off = 128; off > 0; off >>= 1) {
        if (tid < off) red[tid] += red[tid + off];
        __syncthreads();
    }
    if (tid == 0) out[0] = red[0] / (float)n;
}

extern "C" void kernel_launch(void* const* d_in, const int* in_sizes, int n_in,
                              void* d_out, int out_size, void* d_ws, size_t ws_size,
                              hipStream_t stream) {
    const float* psi       = (const float*)d_in[0];
    const float* bank_keys = (const float*)d_in[1];
    const float* bank_vals = (const float*)d_in[2];
    const float* u_halt    = (const float*)d_in[3];
    const float* W_halt    = (const float*)d_in[4];
    const float* b_halt    = (const float*)d_in[5];
    const float* head_mix  = (const float*)d_in[6];
    const float* out_scale = (const float*)d_in[7];
    float* out = (float*)d_out;

    const int BT = in_sizes[0] / FF;    // 4096

    float* ws = (float*)d_ws;
    size_t off = 0;
    float* psi_h  = ws + off; off += (size_t)BT * HH * FF;
    float* merged = ws + off; off += (size_t)BT * FF;     // zero region starts here
    float* cum    = ws + off; off += (size_t)BT * HH;
    float* costv  = ws + off; off += (size_t)BT * HH;
    int*   halted = (int*)(ws + off); off += (size_t)BT * HH;
    float* topw   = ws + off; off += (size_t)BT * HH * KK;
    int*   topi   = (int*)(ws + off); off += (size_t)BT * HH * KK;
    float* norminv = ws + off; off += 16;
    ushort_t* feat_bf = (ushort_t*)(ws + off); off += (size_t)BT * FF / 2;
    ushort_t* keys_bf = (ushort_t*)(ws + off); off += (size_t)HH * NN * FF / 2;
    float* scores = ws + off;
    size_t fixed = off;

    size_t ws_floats = ws_size / 4;
    int RC = BT;
    while (RC > 128 && fixed + (size_t)RC * HH * NN > ws_floats) RC >>= 1;
    int nchunks = BT / RC;

    hipMemsetAsync(merged, 0, ((size_t)BT * FF + 3 * (size_t)BT * HH) * sizeof(float), stream);
    k_unorm<<<1, 256, 0, stream>>>(u_halt, norminv);
    int tot_keys = HH * NN * FF;
    k_cvt_bf<<<(tot_keys + 255) / 256, 256, 0, stream>>>(bank_keys, keys_bf, tot_keys);
    int tot_bf = BT * FF;
    k_cvt_bf<<<(tot_bf + 255) / 256, 256, 0, stream>>>(psi, feat_bf, tot_bf);  // iter-0 feat = psi

    for (int it = 0; it < TMAXI; ++it) {
        for (int c = 0; c < nchunks; ++c) {
            k_gemm_mfma<<<dim3((HH * NN) / BN, RC / BM), 256, 0, stream>>>(
                feat_bf + (size_t)c * RC * FF, keys_bf, scores);
            k_softtop<<<dim3(RC, HH), 256, 0, stream>>>(scores, topw, topi, c * RC);
        }
        k_fused<<<BT, 256, 0, stream>>>(psi, psi_h, bank_vals, topw, topi, u_halt, norminv,
                                        W_halt, b_halt, head_mix, merged, feat_bf,
                                        cum, costv, halted,
                                        (it == 0) ? 1 : 0, (it == TMAXI - 1) ? 1 : 0);
    }
    k_out<<<(tot_bf + 255) / 256, 256, 0, stream>>>(psi, merged, out_scale, out, tot_bf);
    k_costmean<<<1, 256, 0, stream>>>(costv, out + tot_bf, BT * HH);
}